// Round 5
// baseline (204.457 us; speedup 1.0000x reference)
//
#include <hip/hip_runtime.h>
#include <math.h>

#define CC   256      // channels
#define CR   16       // reduced channels
#define SB   16384    // H*W
#define NB   16       // batch
#define ST   32       // spatial tile per block (32 -> ~37 KiB LDS, 4 blocks/CU)
#define NT   (SB/ST)  // 512 tiles per batch
#define LN_EPS 1e-5f

typedef float vfloat4 __attribute__((ext_vector_type(4)));  // builtin-compatible

// ---------------------------------------------------------------------------
// Kernel A (fused): one 32-position spatial tile per block. Stage x[:,tile]
// in LDS (single HBM read of x), folding the w_mask multiply into staging.
// Per-tile softmax numerator + partial context (flash-style).
// b_mask is a scalar on all logits -> cancels in softmax -> dropped.
// grid: NB*NT = 8192 blocks, 256 threads, ~37 KiB LDS -> 4 blocks/CU
// ---------------------------------------------------------------------------
__global__ __launch_bounds__(256) void k_ctx_partial(const float* __restrict__ x,
                                                     const float* __restrict__ w_mask,
                                                     float* __restrict__ pc,
                                                     float* __restrict__ pm,
                                                     float* __restrict__ ps) {
    __shared__ float tile[CC * ST];     // 32 KiB: tile[c*32 + s]
    __shared__ float plog[ST * 33];     // padded logit partials [s][c0], 4.2 KiB
    __shared__ float pl[ST];            // exp(l - m) per s
    __shared__ float wm[CC];            // w_mask copy

    const int t   = threadIdx.x;
    const int bid = blockIdx.x;
    const int b   = bid / NT;
    const int s0  = (bid % NT) * ST;

    wm[t] = w_mask[t];
    __syncthreads();

    // stage x tile + fused logit partial: thread t covers rows c = (t>>3)+32k,
    // float4 at s=(t&7)*4, accumulating v*wm[c] as it goes.
    {
        const int c0 = t >> 3;            // 0..31
        const int s4 = (t & 7) << 2;      // 0,4,...,28
        const float* xb = x + ((size_t)b * CC) * SB + s0 + s4;
        float4 acc = make_float4(0.f, 0.f, 0.f, 0.f);
#pragma unroll
        for (int k = 0; k < 8; ++k) {
            const int c = c0 + (k << 5);
            const float4 v = *reinterpret_cast<const float4*>(xb + (size_t)c * SB);
            *reinterpret_cast<float4*>(&tile[c * ST + s4]) = v;
            const float w = wm[c];
            acc.x += v.x * w; acc.y += v.y * w; acc.z += v.z * w; acc.w += v.w * w;
        }
        plog[(s4 + 0) * 33 + c0] = acc.x;
        plog[(s4 + 1) * 33 + c0] = acc.y;
        plog[(s4 + 2) * 33 + c0] = acc.z;
        plog[(s4 + 3) * 33 + c0] = acc.w;
    }
    __syncthreads();

    // finalize logits + tile softmax numerator on first 32 lanes
    if (t < ST) {
        const int s = t;
        float logit = 0.f;
#pragma unroll
        for (int i = 0; i < 32; ++i) logit += plog[s * 33 + i];
        float m = logit;
#pragma unroll
        for (int off = 16; off > 0; off >>= 1)
            m = fmaxf(m, __shfl_xor(m, off));
        const float p = __expf(logit - m);
        pl[s] = p;
        float sum = p;
#pragma unroll
        for (int off = 16; off > 0; off >>= 1)
            sum += __shfl_xor(sum, off);
        if (s == 0) { pm[bid] = m; ps[bid] = sum; }
    }
    __syncthreads();

    // partial context. thread t = channel; staggered s index -> conflict-free.
    {
        float acc = 0.f;
        const int base = t * ST;
#pragma unroll 8
        for (int j = 0; j < ST; ++j) {
            const int idx = (j + t) & (ST - 1);
            acc += tile[base + idx] * pl[idx];
        }
        pc[(size_t)bid * CC + t] = acc;
    }
}

// ---------------------------------------------------------------------------
// Kernel B: flash-combine across NT=512 tiles per batch + full MLP.
// grid: NB blocks, 256 threads (each thread covers 2 tiles in the reductions).
// ---------------------------------------------------------------------------
__global__ __launch_bounds__(256) void k_combine_mlp(const float* __restrict__ pc,
                                                     const float* __restrict__ pm,
                                                     const float* __restrict__ ps,
                                                     const float* __restrict__ w1,
                                                     const float* __restrict__ b1,
                                                     const float* __restrict__ ln_g,
                                                     const float* __restrict__ ln_b,
                                                     const float* __restrict__ w2,
                                                     const float* __restrict__ b2,
                                                     float* __restrict__ add) {
    const int b = blockIdx.x;
    const int t = threadIdx.x;
    __shared__ float red[256];
    __shared__ float fx[NT];
    __shared__ float ctx[CC];
    __shared__ float tbuf[CR];
    __shared__ float tn[CR];

    const float m_a = pm[b * NT + t];
    const float m_b = pm[b * NT + t + 256];

    // global max over tile maxima
    red[t] = fmaxf(m_a, m_b); __syncthreads();
    for (int st = 128; st > 0; st >>= 1) {
        if (t < st) red[t] = fmaxf(red[t], red[t + st]);
        __syncthreads();
    }
    const float M = red[0]; __syncthreads();

    // rescale factors + global Z
    const float f_a = __expf(m_a - M);
    const float f_b = __expf(m_b - M);
    fx[t] = f_a; fx[t + 256] = f_b;
    red[t] = ps[b * NT + t] * f_a + ps[b * NT + t + 256] * f_b; __syncthreads();
    for (int st = 128; st > 0; st >>= 1) {
        if (t < st) red[t] += red[t + st];
        __syncthreads();
    }
    const float invZ = 1.0f / red[0]; __syncthreads();

    // ctx[c] = sum_tiles pc[tile][c] * fx[tile] / Z   (coalesced over c=t)
    float acc = 0.f;
#pragma unroll 4
    for (int j = 0; j < NT; ++j)
        acc += pc[((size_t)b * NT + j) * CC + t] * fx[j];
    ctx[t] = acc * invZ;
    __syncthreads();

    // MLP: t1 = w1@ctx + b1 ; LN ; ReLU ; add = w2@t1 + b2
    if (t < CR) {
        float a = b1[t];
        const float* w1r = w1 + (size_t)t * CC;
#pragma unroll 8
        for (int c = 0; c < CC; ++c) a += w1r[c] * ctx[c];
        tbuf[t] = a;
    }
    __syncthreads();
    if (t == 0) {
        float mu = 0.f;
        for (int i = 0; i < CR; ++i) mu += tbuf[i];
        mu *= (1.0f / CR);
        float var = 0.f;
        for (int i = 0; i < CR; ++i) { const float d = tbuf[i] - mu; var += d * d; }
        var *= (1.0f / CR);
        const float inv = rsqrtf(var + LN_EPS);
        for (int i = 0; i < CR; ++i) {
            const float v = (tbuf[i] - mu) * inv * ln_g[i] + ln_b[i];
            tn[i] = v > 0.f ? v : 0.f;
        }
    }
    __syncthreads();

    float a = b2[t];
    const float* w2r = w2 + (size_t)t * CR;
#pragma unroll
    for (int o = 0; o < CR; ++o) a += w2r[o] * tn[o];
    add[(size_t)b * CC + t] = a;
}

// ---------------------------------------------------------------------------
// Kernel C: out[b,c,s] = x[b,c,s] + add[b,c].
// REVERSED block order: kernel A streamed x ascending, so the tail of x is
// the L3-resident part. Block 0 reads the highest addresses first (LRU-
// friendly), and this pass leaves the LOW addresses MRU for the next graph
// replay's kernel A (ascending) — boustrophedon reuse across replays.
// Non-temporal out-stores avoid evicting x from L3. 8 floats/thread.
// ---------------------------------------------------------------------------
#define ADD_BLOCKS (NB * CC * SB / 2048)
__global__ __launch_bounds__(256) void k_add(const float* __restrict__ x,
                                             const float* __restrict__ add,
                                             float* __restrict__ out) {
    const size_t idx = ((size_t)(ADD_BLOCKS - 1 - blockIdx.x) * 256 + threadIdx.x) * 8;
    const size_t bc = idx / SB;   // 8 elems never cross a (b,c) boundary
    const float a = add[bc];
    const float4 v0 = *reinterpret_cast<const float4*>(x + idx);
    const float4 v1 = *reinterpret_cast<const float4*>(x + idx + 4);
    vfloat4 o0 = {v0.x + a, v0.y + a, v0.z + a, v0.w + a};
    vfloat4 o1 = {v1.x + a, v1.y + a, v1.z + a, v1.w + a};
    __builtin_nontemporal_store(o0, reinterpret_cast<vfloat4*>(out + idx));
    __builtin_nontemporal_store(o1, reinterpret_cast<vfloat4*>(out + idx + 4));
}

// ---------------------------------------------------------------------------
extern "C" void kernel_launch(void* const* d_in, const int* in_sizes, int n_in,
                              void* d_out, int out_size, void* d_ws, size_t ws_size,
                              hipStream_t stream) {
    const float* x      = (const float*)d_in[0];
    const float* w_mask = (const float*)d_in[1];
    // d_in[2] = b_mask: scalar added to all logits; cancels in softmax.
    const float* w1     = (const float*)d_in[3];
    const float* b1     = (const float*)d_in[4];
    const float* ln_g   = (const float*)d_in[5];
    const float* ln_b   = (const float*)d_in[6];
    const float* w2     = (const float*)d_in[7];
    const float* b2     = (const float*)d_in[8];
    float* out = (float*)d_out;

    // workspace (floats): pc[NB*NT*CC]=2M (8 MiB), pm/ps[NB*NT], add[NB*CC]
    float* ws  = (float*)d_ws;
    float* pc  = ws;                              // 2,097,152
    float* pm  = pc + (size_t)NB * NT * CC;       // 8192
    float* ps  = pm + (size_t)NB * NT;            // 8192
    float* add = ps + (size_t)NB * NT;            // 4096

    k_ctx_partial<<<dim3(NB * NT), dim3(256), 0, stream>>>(x, w_mask, pc, pm, ps);
    k_combine_mlp<<<dim3(NB), dim3(256), 0, stream>>>(pc, pm, ps, w1, b1, ln_g, ln_b, w2, b2, add);
    k_add<<<dim3(ADD_BLOCKS), dim3(256), 0, stream>>>(x, add, out);
}

// Round 6
// 176.661 us; speedup vs baseline: 1.1573x; 1.1573x over previous
//
#include <hip/hip_runtime.h>
#include <math.h>

#define CC   256      // channels
#define CR   16       // reduced channels
#define SB   16384    // H*W
#define NB   16       // batch
#define ST   64       // spatial tile per block
#define NT   (SB/ST)  // 256 tiles per batch
#define LN_EPS 1e-5f

typedef float vfloat4 __attribute__((ext_vector_type(4)));  // builtin-compatible

// ---------------------------------------------------------------------------
// Kernel A (fused): one 64-position spatial tile per block, 1024 threads.
// Stage x[:,tile] in LDS (single HBM read of x), folding the w_mask multiply
// into staging. Per-tile softmax numerator + partial context (flash-style).
// b_mask is a scalar on all logits -> cancels in softmax -> dropped.
// LDS ~74 KiB -> 2 blocks/CU x 16 waves = 32 waves/CU (max occupancy).
// grid: NB*NT = 4096 blocks.
// ---------------------------------------------------------------------------
__global__ __launch_bounds__(1024) void k_ctx_partial(const float* __restrict__ x,
                                                      const float* __restrict__ w_mask,
                                                      float* __restrict__ pc,
                                                      float* __restrict__ pm,
                                                      float* __restrict__ ps) {
    __shared__ float tile[CC * ST];     // 64 KiB: tile[c*64 + s]
    __shared__ float plog[ST * 17];     // logit partials [s][wave], padded
    __shared__ float pl[ST];            // exp(l - m) per s
    __shared__ float wm[CC];            // w_mask copy
    __shared__ float red2[4 * 260];     // pass-2 partials [q][c], padded

    const int t   = threadIdx.x;
    const int bid = blockIdx.x;
    const int b   = bid / NT;
    const int s0  = (bid % NT) * ST;

    if (t < CC) wm[t] = w_mask[t];
    __syncthreads();

    // stage x tile + fused logit partial: thread t covers rows c = (t>>4)+64k,
    // float4 at s=(t&15)*4, accumulating v*wm[c] as it goes.
    {
        const int c0 = t >> 4;            // 0..63
        const int s4 = (t & 15) << 2;     // 0,4,...,60
        const float* xb = x + ((size_t)b * CC) * SB + s0 + s4;
        float4 acc = make_float4(0.f, 0.f, 0.f, 0.f);
#pragma unroll
        for (int k = 0; k < 4; ++k) {
            const int c = c0 + (k << 6);
            const float4 v = *reinterpret_cast<const float4*>(xb + (size_t)c * SB);
            *reinterpret_cast<float4*>(&tile[c * ST + s4]) = v;
            const float w = wm[c];
            acc.x += v.x * w; acc.y += v.y * w; acc.z += v.z * w; acc.w += v.w * w;
        }
        // reduce over the 4 lanes sharing s4 within this wave (l^16, l^32)
        acc.x += __shfl_xor(acc.x, 16); acc.y += __shfl_xor(acc.y, 16);
        acc.z += __shfl_xor(acc.z, 16); acc.w += __shfl_xor(acc.w, 16);
        acc.x += __shfl_xor(acc.x, 32); acc.y += __shfl_xor(acc.y, 32);
        acc.z += __shfl_xor(acc.z, 32); acc.w += __shfl_xor(acc.w, 32);
        const int wv = t >> 6;            // wave 0..15
        if ((t & 63) < 16) {              // one lane per s4-quad per wave
            plog[(s4 + 0) * 17 + wv] = acc.x;
            plog[(s4 + 1) * 17 + wv] = acc.y;
            plog[(s4 + 2) * 17 + wv] = acc.z;
            plog[(s4 + 3) * 17 + wv] = acc.w;
        }
    }
    __syncthreads();

    // finalize logits + tile softmax numerator on first 64 lanes (one wave)
    if (t < ST) {
        float logit = 0.f;
#pragma unroll
        for (int i = 0; i < 16; ++i) logit += plog[t * 17 + i];
        float m = logit;
#pragma unroll
        for (int off = 32; off > 0; off >>= 1)
            m = fmaxf(m, __shfl_xor(m, off));
        const float p = __expf(logit - m);
        pl[t] = p;
        float sum = p;
#pragma unroll
        for (int off = 32; off > 0; off >>= 1)
            sum += __shfl_xor(sum, off);
        if (t == 0) { pm[bid] = m; ps[bid] = sum; }
    }
    __syncthreads();

    // partial context: thread (c = t>>2, q = t&3) sums its s-quarter,
    // staggered so tile/pl reads are <=2-way bank conflicts.
    {
        const int c = t >> 2;             // 0..255
        const int q = t & 3;              // 0..3
        const int base = c * ST + q * 16;
        float acc2 = 0.f;
#pragma unroll
        for (int j = 0; j < 16; ++j) {
            const int idx = (j + c) & 15;
            acc2 += tile[base + idx] * pl[q * 16 + idx];
        }
        red2[q * 260 + c] = acc2;
    }
    __syncthreads();
    if (t < CC)
        pc[(size_t)bid * CC + t] = red2[t] + red2[260 + t] + red2[520 + t] + red2[780 + t];
}

// ---------------------------------------------------------------------------
// Kernel B: flash-combine across NT=256 tiles per batch + full MLP.
// grid: NB blocks, 256 threads.
// ---------------------------------------------------------------------------
__global__ __launch_bounds__(256) void k_combine_mlp(const float* __restrict__ pc,
                                                     const float* __restrict__ pm,
                                                     const float* __restrict__ ps,
                                                     const float* __restrict__ w1,
                                                     const float* __restrict__ b1,
                                                     const float* __restrict__ ln_g,
                                                     const float* __restrict__ ln_b,
                                                     const float* __restrict__ w2,
                                                     const float* __restrict__ b2,
                                                     float* __restrict__ add) {
    const int b = blockIdx.x;
    const int t = threadIdx.x;
    __shared__ float red[256];
    __shared__ float fx[NT];
    __shared__ float ctx[CC];
    __shared__ float tbuf[CR];
    __shared__ float tn[CR];

    // global max over tile maxima
    const float m_t = pm[b * NT + t];
    red[t] = m_t; __syncthreads();
    for (int st = 128; st > 0; st >>= 1) {
        if (t < st) red[t] = fmaxf(red[t], red[t + st]);
        __syncthreads();
    }
    const float M = red[0]; __syncthreads();

    // rescale factors + global Z
    const float f = __expf(m_t - M);
    fx[t] = f;
    red[t] = ps[b * NT + t] * f; __syncthreads();
    for (int st = 128; st > 0; st >>= 1) {
        if (t < st) red[t] += red[t + st];
        __syncthreads();
    }
    const float invZ = 1.0f / red[0]; __syncthreads();

    // ctx[c] = sum_tiles pc[tile][c] * fx[tile] / Z   (coalesced over c=t)
    float acc = 0.f;
#pragma unroll 4
    for (int j = 0; j < NT; ++j)
        acc += pc[((size_t)b * NT + j) * CC + t] * fx[j];
    ctx[t] = acc * invZ;
    __syncthreads();

    // MLP: t1 = w1@ctx + b1 ; LN ; ReLU ; add = w2@t1 + b2
    if (t < CR) {
        float a = b1[t];
        const float* w1r = w1 + (size_t)t * CC;
#pragma unroll 8
        for (int c = 0; c < CC; ++c) a += w1r[c] * ctx[c];
        tbuf[t] = a;
    }
    __syncthreads();
    if (t == 0) {
        float mu = 0.f;
        for (int i = 0; i < CR; ++i) mu += tbuf[i];
        mu *= (1.0f / CR);
        float var = 0.f;
        for (int i = 0; i < CR; ++i) { const float d = tbuf[i] - mu; var += d * d; }
        var *= (1.0f / CR);
        const float inv = rsqrtf(var + LN_EPS);
        for (int i = 0; i < CR; ++i) {
            const float v = (tbuf[i] - mu) * inv * ln_g[i] + ln_b[i];
            tn[i] = v > 0.f ? v : 0.f;
        }
    }
    __syncthreads();

    float a = b2[t];
    const float* w2r = w2 + (size_t)t * CR;
#pragma unroll
    for (int o = 0; o < CR; ++o) a += w2r[o] * tn[o];
    add[(size_t)b * CC + t] = a;
}

// ---------------------------------------------------------------------------
// Kernel C: out[b,c,s] = x[b,c,s] + add[b,c]. Non-temporal out-stores keep x
// resident in Infinity Cache so the x re-read is an L3 hit where possible.
// Forward order (round-4 config). 8 floats/thread.
// ---------------------------------------------------------------------------
__global__ __launch_bounds__(256) void k_add(const float* __restrict__ x,
                                             const float* __restrict__ add,
                                             float* __restrict__ out) {
    const size_t idx = ((size_t)blockIdx.x * 256 + threadIdx.x) * 8;
    const size_t bc = idx / SB;   // 8 elems never cross a (b,c) boundary
    const float a = add[bc];
    const float4 v0 = *reinterpret_cast<const float4*>(x + idx);
    const float4 v1 = *reinterpret_cast<const float4*>(x + idx + 4);
    vfloat4 o0 = {v0.x + a, v0.y + a, v0.z + a, v0.w + a};
    vfloat4 o1 = {v1.x + a, v1.y + a, v1.z + a, v1.w + a};
    __builtin_nontemporal_store(o0, reinterpret_cast<vfloat4*>(out + idx));
    __builtin_nontemporal_store(o1, reinterpret_cast<vfloat4*>(out + idx + 4));
}

// ---------------------------------------------------------------------------
extern "C" void kernel_launch(void* const* d_in, const int* in_sizes, int n_in,
                              void* d_out, int out_size, void* d_ws, size_t ws_size,
                              hipStream_t stream) {
    const float* x      = (const float*)d_in[0];
    const float* w_mask = (const float*)d_in[1];
    // d_in[2] = b_mask: scalar added to all logits; cancels in softmax.
    const float* w1     = (const float*)d_in[3];
    const float* b1     = (const float*)d_in[4];
    const float* ln_g   = (const float*)d_in[5];
    const float* ln_b   = (const float*)d_in[6];
    const float* w2     = (const float*)d_in[7];
    const float* b2     = (const float*)d_in[8];
    float* out = (float*)d_out;

    // workspace (floats): pc[NB*NT*CC]=1M, pm/ps[NB*NT], add[NB*CC]
    float* ws  = (float*)d_ws;
    float* pc  = ws;                              // 1,048,576
    float* pm  = pc + (size_t)NB * NT * CC;       // 4096
    float* ps  = pm + (size_t)NB * NT;            // 4096
    float* add = ps + (size_t)NB * NT;            // 4096

    k_ctx_partial<<<dim3(NB * NT), dim3(1024), 0, stream>>>(x, w_mask, pc, pm, ps);
    k_combine_mlp<<<dim3(NB), dim3(256), 0, stream>>>(pc, pm, ps, w1, b1, ln_g, ln_b, w2, b2, add);
    k_add<<<dim3(NB * CC * SB / 2048), dim3(256), 0, stream>>>(x, add, out);
}

// Round 7
// 170.427 us; speedup vs baseline: 1.1997x; 1.0366x over previous
//
#include <hip/hip_runtime.h>
#include <math.h>

#define CC   256      // channels
#define CR   16       // reduced channels
#define SB   16384    // H*W
#define NB   16       // batch
#define ST   64       // spatial tile per block
#define NT   (SB/ST)  // 256 tiles per batch
#define LN_EPS 1e-5f

typedef float vfloat4 __attribute__((ext_vector_type(4)));  // builtin-compatible

// ---------------------------------------------------------------------------
// Kernel A (fused, register-resident): one 64-position spatial tile per
// block, 256 threads. Thread t holds channels c = (t>>4) + 16k (k=0..15) at
// s4 = (t&15)*4 in 16 float4 REGISTERS (no LDS tile). Logit partial is
// accumulated during load; after softmax numerator pl[] is published via a
// tiny LDS buffer, the context partial is computed from registers and
// reduced through a padded 17-KiB LDS array.
// b_mask is a scalar on all logits -> cancels in softmax -> dropped.
// grid: NB*NT = 4096 blocks. LDS ~19 KiB, VGPR ~100.
// ---------------------------------------------------------------------------
__global__ __launch_bounds__(256) void k_ctx_partial(const float* __restrict__ x,
                                                     const float* __restrict__ w_mask,
                                                     float* __restrict__ pc,
                                                     float* __restrict__ pm,
                                                     float* __restrict__ ps) {
    __shared__ float plog[ST * 5];      // logit partials [s][wave 0..3], pad 5
    __shared__ float pl[ST];            // exp(l - m) per s
    __shared__ float wm[CC];            // w_mask copy
    __shared__ float red2[CC * 17];     // context partials [c][group], pad 17

    const int t   = threadIdx.x;
    const int bid = blockIdx.x;
    const int b   = bid / NT;
    const int s0  = (bid % NT) * ST;

    wm[t] = w_mask[t];
    __syncthreads();

    const int g  = t >> 4;              // channel-group base 0..15
    const int i  = t & 15;              // s4 slot 0..15
    const int s4 = i << 2;

    // stage into registers + fused logit partial
    const float* xb = x + (size_t)b * CC * SB + s0 + s4;
    float4 v[16];
    float4 acc = make_float4(0.f, 0.f, 0.f, 0.f);
#pragma unroll
    for (int k = 0; k < 16; ++k) {
        const int c = g + (k << 4);
        v[k] = *reinterpret_cast<const float4*>(xb + (size_t)c * SB);
        const float w = wm[c];
        acc.x += v[k].x * w; acc.y += v[k].y * w;
        acc.z += v[k].z * w; acc.w += v[k].w * w;
    }
    // reduce logit partial across the 4 lanes sharing s4 within this wave
    acc.x += __shfl_xor(acc.x, 16); acc.y += __shfl_xor(acc.y, 16);
    acc.z += __shfl_xor(acc.z, 16); acc.w += __shfl_xor(acc.w, 16);
    acc.x += __shfl_xor(acc.x, 32); acc.y += __shfl_xor(acc.y, 32);
    acc.z += __shfl_xor(acc.z, 32); acc.w += __shfl_xor(acc.w, 32);
    const int wv = t >> 6;              // wave 0..3
    if ((t & 63) < 16) {
        plog[(s4 + 0) * 5 + wv] = acc.x;
        plog[(s4 + 1) * 5 + wv] = acc.y;
        plog[(s4 + 2) * 5 + wv] = acc.z;
        plog[(s4 + 3) * 5 + wv] = acc.w;
    }
    __syncthreads();

    // finalize logits + tile softmax numerator on wave 0
    if (t < ST) {
        const float logit = plog[t * 5 + 0] + plog[t * 5 + 1]
                          + plog[t * 5 + 2] + plog[t * 5 + 3];
        float m = logit;
#pragma unroll
        for (int off = 32; off > 0; off >>= 1)
            m = fmaxf(m, __shfl_xor(m, off));
        const float p = __expf(logit - m);
        pl[t] = p;
        float sum = p;
#pragma unroll
        for (int off = 32; off > 0; off >>= 1)
            sum += __shfl_xor(sum, off);
        if (t == 0) { pm[bid] = m; ps[bid] = sum; }
    }
    __syncthreads();

    // context partials straight from registers
    const float p0 = pl[s4 + 0], p1 = pl[s4 + 1];
    const float p2 = pl[s4 + 2], p3 = pl[s4 + 3];
#pragma unroll
    for (int k = 0; k < 16; ++k) {
        const int c = g + (k << 4);
        red2[c * 17 + i] = v[k].x * p0 + v[k].y * p1 + v[k].z * p2 + v[k].w * p3;
    }
    __syncthreads();

    // final 16-way sum per channel (t = channel), stride-17 -> conflict-free
    float s = 0.f;
#pragma unroll
    for (int j = 0; j < 16; ++j) s += red2[t * 17 + j];
    pc[(size_t)bid * CC + t] = s;
}

// ---------------------------------------------------------------------------
// Kernel B: flash-combine across NT=256 tiles per batch + full MLP.
// grid: NB blocks, 256 threads.
// ---------------------------------------------------------------------------
__global__ __launch_bounds__(256) void k_combine_mlp(const float* __restrict__ pc,
                                                     const float* __restrict__ pm,
                                                     const float* __restrict__ ps,
                                                     const float* __restrict__ w1,
                                                     const float* __restrict__ b1,
                                                     const float* __restrict__ ln_g,
                                                     const float* __restrict__ ln_b,
                                                     const float* __restrict__ w2,
                                                     const float* __restrict__ b2,
                                                     float* __restrict__ add) {
    const int b = blockIdx.x;
    const int t = threadIdx.x;
    __shared__ float red[256];
    __shared__ float fx[NT];
    __shared__ float ctx[CC];
    __shared__ float tbuf[CR];
    __shared__ float tn[CR];

    // global max over tile maxima
    const float m_t = pm[b * NT + t];
    red[t] = m_t; __syncthreads();
    for (int st = 128; st > 0; st >>= 1) {
        if (t < st) red[t] = fmaxf(red[t], red[t + st]);
        __syncthreads();
    }
    const float M = red[0]; __syncthreads();

    // rescale factors + global Z
    const float f = __expf(m_t - M);
    fx[t] = f;
    red[t] = ps[b * NT + t] * f; __syncthreads();
    for (int st = 128; st > 0; st >>= 1) {
        if (t < st) red[t] += red[t + st];
        __syncthreads();
    }
    const float invZ = 1.0f / red[0]; __syncthreads();

    // ctx[c] = sum_tiles pc[tile][c] * fx[tile] / Z   (coalesced over c=t)
    float acc = 0.f;
#pragma unroll 4
    for (int j = 0; j < NT; ++j)
        acc += pc[((size_t)b * NT + j) * CC + t] * fx[j];
    ctx[t] = acc * invZ;
    __syncthreads();

    // MLP: t1 = w1@ctx + b1 ; LN ; ReLU ; add = w2@t1 + b2
    if (t < CR) {
        float a = b1[t];
        const float* w1r = w1 + (size_t)t * CC;
#pragma unroll 8
        for (int c = 0; c < CC; ++c) a += w1r[c] * ctx[c];
        tbuf[t] = a;
    }
    __syncthreads();
    if (t == 0) {
        float mu = 0.f;
        for (int i = 0; i < CR; ++i) mu += tbuf[i];
        mu *= (1.0f / CR);
        float var = 0.f;
        for (int i = 0; i < CR; ++i) { const float d = tbuf[i] - mu; var += d * d; }
        var *= (1.0f / CR);
        const float inv = rsqrtf(var + LN_EPS);
        for (int i = 0; i < CR; ++i) {
            const float v = (tbuf[i] - mu) * inv * ln_g[i] + ln_b[i];
            tn[i] = v > 0.f ? v : 0.f;
        }
    }
    __syncthreads();

    float a = b2[t];
    const float* w2r = w2 + (size_t)t * CR;
#pragma unroll
    for (int o = 0; o < CR; ++o) a += w2r[o] * tn[o];
    add[(size_t)b * CC + t] = a;
}

// ---------------------------------------------------------------------------
// Kernel C: out[b,c,s] = x[b,c,s] + add[b,c]. Non-temporal out-stores keep x
// resident in Infinity Cache so the x re-read is an L3 hit where possible.
// 8 floats/thread. grid: NB*CC*SB/2048 = 32768 blocks.
// ---------------------------------------------------------------------------
__global__ __launch_bounds__(256) void k_add(const float* __restrict__ x,
                                             const float* __restrict__ add,
                                             float* __restrict__ out) {
    const size_t idx = ((size_t)blockIdx.x * 256 + threadIdx.x) * 8;
    const size_t bc = idx / SB;   // 8 elems never cross a (b,c) boundary
    const float a = add[bc];
    const float4 v0 = *reinterpret_cast<const float4*>(x + idx);
    const float4 v1 = *reinterpret_cast<const float4*>(x + idx + 4);
    vfloat4 o0 = {v0.x + a, v0.y + a, v0.z + a, v0.w + a};
    vfloat4 o1 = {v1.x + a, v1.y + a, v1.z + a, v1.w + a};
    __builtin_nontemporal_store(o0, reinterpret_cast<vfloat4*>(out + idx));
    __builtin_nontemporal_store(o1, reinterpret_cast<vfloat4*>(out + idx + 4));
}

// ---------------------------------------------------------------------------
extern "C" void kernel_launch(void* const* d_in, const int* in_sizes, int n_in,
                              void* d_out, int out_size, void* d_ws, size_t ws_size,
                              hipStream_t stream) {
    const float* x      = (const float*)d_in[0];
    const float* w_mask = (const float*)d_in[1];
    // d_in[2] = b_mask: scalar added to all logits; cancels in softmax.
    const float* w1     = (const float*)d_in[3];
    const float* b1     = (const float*)d_in[4];
    const float* ln_g   = (const float*)d_in[5];
    const float* ln_b   = (const float*)d_in[6];
    const float* w2     = (const float*)d_in[7];
    const float* b2     = (const float*)d_in[8];
    float* out = (float*)d_out;

    // workspace (floats): pc[NB*NT*CC]=1M, pm/ps[NB*NT], add[NB*CC]
    float* ws  = (float*)d_ws;
    float* pc  = ws;                              // 1,048,576
    float* pm  = pc + (size_t)NB * NT * CC;       // 4096
    float* ps  = pm + (size_t)NB * NT;            // 4096
    float* add = ps + (size_t)NB * NT;            // 4096

    k_ctx_partial<<<dim3(NB * NT), dim3(256), 0, stream>>>(x, w_mask, pc, pm, ps);
    k_combine_mlp<<<dim3(NB), dim3(256), 0, stream>>>(pc, pm, ps, w1, b1, ln_g, ln_b, w2, b2, add);
    k_add<<<dim3(NB * CC * SB / 2048), dim3(256), 0, stream>>>(x, add, out);
}